// Round 8
// baseline (362.301 us; speedup 1.0000x reference)
//
#include <hip/hip_runtime.h>
#include <hip/hip_cooperative_groups.h>
#include <math.h>

namespace cg = cooperative_groups;

constexpr int Bc = 2, Lc = 256, DMc = 256, Hc = 8, DHc = 32;
constexpr float LOG2E = 1.4426950408889634f;
constexpr float RSQRT_DH = 0.17677669529663687f; // 1/sqrt(32)
#define EXP2 __builtin_amdgcn_exp2f

// Gaussian-mixture tabulation parameters (see earlier rounds).
constexpr int   NTAB = 512;
constexpr float SIG0 = 0.02f;

// ===========================================================================
// Phase-1 roles, 512-thread versions. Per-output math/order identical to the
// proven 4-kernel R5 build (bitwise-same results).
// ===========================================================================
__device__ __forceinline__ float mixsum(const float4* __restrict__ prm, float x) {
    float acc = 0.f;
    #pragma unroll 8
    for (int q = 0; q < 128; ++q) {
        float4 p = prm[q];          // (mu, n, w_masked, 0), wave-uniform ds_read
        float d0 = x - p.x;
        acc = fmaf(p.z, EXP2(d0 * d0 * p.y), acc);
    }
    return acc;
}

__device__ __forceinline__ void role_tab(int bx,
    const float* __restrict__ mu, const float* __restrict__ sg, const float* __restrict__ w,
    float4* __restrict__ TAB, float4* __restrict__ NLIST, int* __restrict__ NCNT,
    float* smem, int tid)
{
    float4* prm = (float4*)smem;      // 128 float4 = 512 floats
    float*  fs  = smem + 512;         // 260 floats
    int*    lcnt = (int*)(smem + 772);
    int hm = bx >> 2, chunk = bx & 3;      // hm = h*4+tau
    int h = hm >> 2, tau = hm & 3;

    if (tid == 0) *lcnt = 0;
    __syncthreads();
    if (tid < 128) {
        int d = tid >> 2, k = tid & 3;
        int off = h * 512 + d * 16 + tau * 4 + k;
        float s  = sg[off];
        float mv = mu[off], wv = w[off];
        float n = -(0.5f * LOG2E) / (s * s);
        bool narrow = (s < SIG0);
        prm[tid] = make_float4(mv, n, narrow ? 0.0f : wv, 0.0f);
        if (chunk == 0 && narrow) {
            int slot = atomicAdd(lcnt, 1);      // order irrelevant: summed later
            NLIST[hm * 128 + slot] = make_float4(mv, n, wv, 0.0f);
        }
    }
    __syncthreads();
    if (chunk == 0 && tid == 0) NCNT[hm] = *lcnt;

    if (tid < 257)
        fs[tid] = mixsum(prm, (float)(chunk * 256 + tid) * (1.0f / 1024.0f));
    __syncthreads();

    if (tid < 128) {
        float f0 = fs[tid * 2], fm = fs[tid * 2 + 1], f1 = fs[tid * 2 + 2];
        float c2 = 2.0f * (f0 + f1 - 2.0f * fm);
        float c1 = f1 - f0 - c2;
        TAB[hm * NTAB + chunk * 128 + tid] = make_float4(f0, c1, c2, 0.0f);
    }
}

// gabs, 512 threads: unit = (b, h, half of 128 i-rows) -> 32 units.
__device__ __forceinline__ void role_gabs(int idx, const float* __restrict__ t,
                                          const float* __restrict__ mu, const float* __restrict__ sg,
                                          const float* __restrict__ w, float* __restrict__ gabs,
                                          float* smem, int tid) {
    int h = idx & 7, b = (idx >> 3) & 1, half = idx >> 4;   // half: 0/1
    float* ns  = smem;          // 512 (input layout d*16+tg*4+k)
    float* red = smem + 512;    // 4 x 128
    {
        float s = sg[h * 512 + tid];
        ns[tid] = -(0.5f * LOG2E) / (s * s);
    }
    __syncthreads();
    int l = tid & 127, tg = tid >> 7;
    int i = half * 128 + l;
    float tv = t[(b * Lc + i) * 4 + tg];
    const float* muB = mu + h * 512 + tg * 4;
    const float* wB  = w  + h * 512 + tg * 4;
    const float* nsB = ns + tg * 4;
    float acc = 0.f;
    #pragma unroll 4
    for (int d = 0; d < 32; ++d) {
        float4 m4 = *(const float4*)(muB + d * 16);
        float4 w4 = *(const float4*)(wB  + d * 16);
        float4 n4 = *(const float4*)(nsB + d * 16);
        float d0 = tv - m4.x; acc = fmaf(w4.x, EXP2(d0 * d0 * n4.x), acc);
        float d1 = tv - m4.y; acc = fmaf(w4.y, EXP2(d1 * d1 * n4.y), acc);
        float d2 = tv - m4.z; acc = fmaf(w4.z, EXP2(d2 * d2 * n4.z), acc);
        float d3 = tv - m4.w; acc = fmaf(w4.w, EXP2(d3 * d3 * n4.w), acc);
    }
    red[tg * 128 + l] = acc;
    __syncthreads();
    if (tid < 128)
        gabs[(b * Hc + h) * Lc + half * 128 + tid] =
            (red[tid] + red[128 + tid] + red[256 + tid] + red[384 + tid]) * (1.0f / 32.0f);
}

// QKV, 512 threads: 64x64 tile, K-chunk 32, 2x4 accum. 96 units (3z x 8m x 4n).
__device__ __forceinline__ void role_qkv(int u, const float* __restrict__ x,
                                         const float* __restrict__ WQ, const float* __restrict__ WK,
                                         const float* __restrict__ WV,
                                         float* __restrict__ Qb, float* __restrict__ Kb,
                                         float* __restrict__ Vb, float* smem, int tid) {
    constexpr int GP = 68;
    int z = u >> 5, r = u & 31;
    int m0 = (r >> 2) * 64, n0 = (r & 3) * 64;   // m over 512 rows (2b x 256), n over 256
    const float* W = (z == 0) ? WQ : (z == 1) ? WK : WV;
    float* C = (z == 0) ? Qb : (z == 1) ? Kb : Vb;
    float sc = (z == 0) ? RSQRT_DH : 1.0f;
    float* As = smem;                 // [32][GP] k-major
    float* Ws = smem + 32 * GP;
    int rr = tid >> 3, c4 = (tid & 7) * 4;
    int tx = tid & 15, ty = tid >> 4;            // ty 0..31
    int i2 = ty * 2, j4 = tx * 4;
    float acc[2][4] = {};
    for (int k0 = 0; k0 < 256; k0 += 32) {
        float4 av = *(const float4*)(x + (size_t)(m0 + rr) * DMc + k0 + c4);
        float4 wv = *(const float4*)(W + (size_t)(n0 + rr) * DMc + k0 + c4);
        const float* a_ = (const float*)&av;
        const float* w_ = (const float*)&wv;
        #pragma unroll
        for (int q = 0; q < 4; ++q) {
            As[(c4 + q) * GP + rr] = a_[q];
            Ws[(c4 + q) * GP + rr] = w_[q];
        }
        __syncthreads();
        #pragma unroll 8
        for (int k = 0; k < 32; ++k) {
            float2 a2 = *(const float2*)(As + k * GP + i2);
            float4 w4 = *(const float4*)(Ws + k * GP + j4);
            const float* aa = (const float*)&a2;
            const float* ww = (const float*)&w4;
            #pragma unroll
            for (int uu = 0; uu < 2; ++uu)
                #pragma unroll
                for (int vv = 0; vv < 4; ++vv)
                    acc[uu][vv] = fmaf(aa[uu], ww[vv], acc[uu][vv]);
        }
        __syncthreads();
    }
    #pragma unroll
    for (int uu = 0; uu < 2; ++uu)
        #pragma unroll
        for (int vv = 0; vv < 4; ++vv)
            C[(size_t)(m0 + i2 + uu) * DMc + n0 + j4 + vv] = acc[uu][vv] * sc;
}

// ===========================================================================
// k_fused: single cooperative kernel, 256 blocks x 512 threads, 4 phases.
// ===========================================================================
__global__ void __launch_bounds__(512) k_fused(
    const float* __restrict__ x, const float* __restrict__ t,
    const float* __restrict__ WQ, const float* __restrict__ WK, const float* __restrict__ WV,
    const float* __restrict__ WO, const float* __restrict__ bO,
    const float* __restrict__ mu_a, const float* __restrict__ sg_a, const float* __restrict__ w_a,
    const float* __restrict__ mu_r, const float* __restrict__ sg_r, const float* __restrict__ w_r,
    const float* __restrict__ alpha, const float* __restrict__ beta, const float* __restrict__ gamma,
    float* __restrict__ out,
    float* __restrict__ Qb, float* __restrict__ Kb, float* __restrict__ Vb,
    float* __restrict__ AO, float* __restrict__ GA, float* __restrict__ GR,
    float4* __restrict__ TAB, float4* __restrict__ NLIST, int* __restrict__ NCNT)
{
    __shared__ __align__(16) float smem[12864];   // 51456 B: max(phase needs)
    cg::grid_group grid = cg::this_grid();
    int bx = blockIdx.x;
    int tid = threadIdx.x;

    // ---------------- Phase 1: tab | gabs | QKV (256 units exactly) --------
    if (bx < 128)      role_tab(bx, mu_r, sg_r, w_r, TAB, NLIST, NCNT, smem, tid);
    else if (bx < 160) role_gabs(bx - 128, t, mu_a, sg_a, w_a, GA, smem, tid);
    else               role_qkv(bx - 160, x, WQ, WK, WV, Qb, Kb, Vb, smem, tid);

    __threadfence();
    grid.sync();

    // ---------------- Phase 2: S,P + modulation + g_rel epilogue -----------
    {
        constexpr int PITCH = 68;
        int it = bx & 3, jt = (bx >> 2) & 3, bh = bx >> 4;
        int b = bh >> 3, h = bh & 7;
        int i0 = it * 64, j0 = jt * 64;
        float* sQ  = smem;
        float* sK  = smem + 32 * PITCH;
        float* sXi = smem + 64 * PITCH;
        float* sXj = smem + 96 * PITCH;

        {   // 512 threads: each stages one float4 per array (64 rows x 32 cols)
            int r = tid >> 3;
            int c4 = (tid & 7) * 4;
            float4 qv = *(const float4*)(Qb + ((size_t)(b * Lc + i0 + r) * DMc + h * DHc + c4));
            float4 kv = *(const float4*)(Kb + ((size_t)(b * Lc + j0 + r) * DMc + h * DHc + c4));
            float4 xi = *(const float4*)(x  + ((size_t)(b * Lc + i0 + r) * DMc + h * DHc + c4));
            float4 xj = *(const float4*)(x  + ((size_t)(b * Lc + j0 + r) * DMc + h * DHc + c4));
            const float* q_ = (const float*)&qv; const float* k_ = (const float*)&kv;
            const float* a_ = (const float*)&xi; const float* c_ = (const float*)&xj;
            #pragma unroll
            for (int u = 0; u < 4; ++u) {
                sQ [(c4 + u) * PITCH + r] = q_[u];
                sK [(c4 + u) * PITCH + r] = k_[u];
                sXi[(c4 + u) * PITCH + r] = a_[u];
                sXj[(c4 + u) * PITCH + r] = c_[u];
            }
        }
        __syncthreads();

        int tx = tid & 15, ty = tid >> 4;    // ty in [0,32)
        int i2 = ty * 2, j4 = tx * 4;
        float accS[2][4] = {}, accP[2][4] = {};
        #pragma unroll 4
        for (int k = 0; k < 32; ++k) {
            float2 qa = *(const float2*)(sQ  + k * PITCH + i2);
            float4 kb = *(const float4*)(sK  + k * PITCH + j4);
            float2 xa = *(const float2*)(sXi + k * PITCH + i2);
            float4 xb = *(const float4*)(sXj + k * PITCH + j4);
            const float* qa_ = (const float*)&qa; const float* kb_ = (const float*)&kb;
            const float* xa_ = (const float*)&xa; const float* xb_ = (const float*)&xb;
            #pragma unroll
            for (int u = 0; u < 2; ++u)
                #pragma unroll
                for (int v = 0; v < 4; ++v) {
                    accS[u][v] = fmaf(qa_[u], kb_[v], accS[u][v]);
                    accP[u][v] = fmaf(xa_[u], xb_[v], accP[u][v]);
                }
        }

        // stage per-head table into the (now dead) tile LDS
        __syncthreads();
        float4* tab = (float4*)smem;         // 2048 float4 = 32 KB
        {
            const float4* src = TAB + (size_t)h * 4 * NTAB;
            #pragma unroll
            for (int u = 0; u < 4; ++u)
                tab[tid + u * 512] = src[tid + u * 512];
        }
        __syncthreads();

        float4 tiv[2], tjv[4];
        #pragma unroll
        for (int u = 0; u < 2; ++u)
            tiv[u] = *(const float4*)(t + (size_t)(b * Lc + i0 + i2 + u) * 4);
        #pragma unroll
        for (int v = 0; v < 4; ++v)
            tjv[v] = *(const float4*)(t + (size_t)(b * Lc + j0 + j4 + v) * 4);

        float g8[2][4] = {};
        #pragma unroll
        for (int tg = 0; tg < 4; ++tg) {
            float xv[2][4];
            #pragma unroll
            for (int u = 0; u < 2; ++u) {
                float tiu = ((const float*)&tiv[u])[tg];
                #pragma unroll
                for (int v = 0; v < 4; ++v) {
                    float xx = fabsf(tiu - ((const float*)&tjv[v])[tg]);
                    xv[u][v] = xx;
                    float xs = xx * (float)NTAB;
                    int iu = min((int)xs, NTAB - 1);
                    float uu = xs - (float)iu;
                    float4 c = tab[tg * NTAB + iu];             // per-lane LDS gather
                    g8[u][v] += fmaf(uu, fmaf(uu, c.z, c.y), c.x);
                }
            }
            int cn = NCNT[h * 4 + tg];                          // block-uniform
            for (int nn = 0; nn < cn; ++nn) {
                float4 q = NLIST[(h * 4 + tg) * 128 + nn];      // uniform s_load
                #pragma unroll
                for (int u = 0; u < 2; ++u)
                    #pragma unroll
                    for (int v = 0; v < 4; ++v) {
                        float d0 = xv[u][v] - q.x;
                        g8[u][v] = fmaf(q.z, EXP2(d0 * d0 * q.y), g8[u][v]);
                    }
            }
        }

        float la = alpha[h], lb = beta[h], lg = gamma[h];
        constexpr float SC = 1.0f / 32.0f;
        float* gb = GR + (size_t)bh * (Lc * Lc);
        #pragma unroll
        for (int u = 0; u < 2; ++u) {
            int i = i0 + i2 + u;
            float gi2 = 2.0f * la * GA[bh * Lc + i];
            float* addr = gb + (size_t)i * Lc + j0 + j4;
            float4 o;
            o.x = accS[u][0] * fmaf(accP[u][0], fmaf(lb, g8[u][0] * SC, gi2), lg);
            o.y = accS[u][1] * fmaf(accP[u][1], fmaf(lb, g8[u][1] * SC, gi2), lg);
            o.z = accS[u][2] * fmaf(accP[u][2], fmaf(lb, g8[u][2] * SC, gi2), lg);
            o.w = accS[u][3] * fmaf(accP[u][3], fmaf(lb, g8[u][3] * SC, gi2), lg);
            *(float4*)addr = o;   // pure store
        }
    }

    __threadfence();
    grid.sync();

    // ---------------- Phase 3: softmax + PV --------------------------------
    {
        int it = bx & 15, bh = bx >> 4;
        int b = bh >> 3, h = bh & 7;
        int i0 = it * 16;
        float* sP = smem;              // 16 x 260
        float* sV = smem + 4160;       // 256 x 34
        int i = tid >> 5, l = tid & 31;

        const float* row = GR + (size_t)bh * (Lc * Lc) + (size_t)(i0 + i) * Lc + l * 8;
        float4 p0 = *(const float4*)(row);
        float4 p1 = *(const float4*)(row + 4);
        float m = fmaxf(fmaxf(fmaxf(p0.x, p0.y), fmaxf(p0.z, p0.w)),
                        fmaxf(fmaxf(p1.x, p1.y), fmaxf(p1.z, p1.w)));
        #pragma unroll
        for (int s = 1; s < 32; s <<= 1) m = fmaxf(m, __shfl_xor(m, s, 32));
        float4 e0, e1;
        e0.x = EXP2((p0.x - m) * LOG2E); e0.y = EXP2((p0.y - m) * LOG2E);
        e0.z = EXP2((p0.z - m) * LOG2E); e0.w = EXP2((p0.w - m) * LOG2E);
        e1.x = EXP2((p1.x - m) * LOG2E); e1.y = EXP2((p1.y - m) * LOG2E);
        e1.z = EXP2((p1.z - m) * LOG2E); e1.w = EXP2((p1.w - m) * LOG2E);
        float sum = ((e0.x + e0.y) + (e0.z + e0.w)) + ((e1.x + e1.y) + (e1.z + e1.w));
        #pragma unroll
        for (int s = 1; s < 32; s <<= 1) sum += __shfl_xor(sum, s, 32);
        float rs = 1.0f / sum;
        *(float4*)(sP + i * 260 + l * 8)     = e0;
        *(float4*)(sP + i * 260 + l * 8 + 4) = e1;

        {   // stage V: 512 threads x 4 rows x float4
            int jr = tid >> 3, c4 = (tid & 7) * 4;
            #pragma unroll
            for (int u = 0; u < 4; ++u) {
                int j = jr + u * 64;
                *(float4*)(sV + j * 34 + c4) =
                    *(const float4*)(Vb + ((size_t)(b * Lc + j) * DMc + h * DHc + c4));
            }
        }
        __syncthreads();

        int d = l;
        float o0 = 0.f;
        #pragma unroll 4
        for (int j4 = 0; j4 < 256; j4 += 4) {
            float4 p4 = *(const float4*)(sP + i * 260 + j4);
            float v0 = sV[(j4 + 0) * 34 + d];
            float v1 = sV[(j4 + 1) * 34 + d];
            float v2 = sV[(j4 + 2) * 34 + d];
            float v3 = sV[(j4 + 3) * 34 + d];
            o0 = fmaf(p4.x, v0, o0); o0 = fmaf(p4.y, v1, o0);
            o0 = fmaf(p4.z, v2, o0); o0 = fmaf(p4.w, v3, o0);
        }
        AO[((size_t)(b * Lc + i0 + i) * DMc + h * DHc + d)] = o0 * rs;
        __syncthreads();   // sP/sV dead before phase 4 reuses smem
    }

    __threadfence();
    grid.sync();

    // ---------------- Phase 4: out = AO @ WO^T + bO ------------------------
    if (bx < 128) {
        int mt = bx >> 3, nt = bx & 7;        // 16 x 8 tiles of 32x32
        int m0 = mt * 32, n0 = nt * 32;       // m over 512 rows
        float* As = smem;                     // [64][33] k-major = 2112
        float* Ws = smem + 2112;
        int rr = tid >> 4;                    // 0..31
        int c4 = (tid & 15) * 4;              // 0..60
        int ty = tid >> 4, tx = tid & 15;
        float acc0 = 0.f, acc1 = 0.f;
        for (int k0 = 0; k0 < 256; k0 += 64) {
            float4 av = *(const float4*)(AO + (size_t)(m0 + rr) * DMc + k0 + c4);
            float4 wv = *(const float4*)(WO + (size_t)(n0 + rr) * DMc + k0 + c4);
            const float* a_ = (const float*)&av;
            const float* w_ = (const float*)&wv;
            #pragma unroll
            for (int q = 0; q < 4; ++q) {
                As[(c4 + q) * 33 + rr] = a_[q];
                Ws[(c4 + q) * 33 + rr] = w_[q];
            }
            __syncthreads();
            #pragma unroll 8
            for (int k = 0; k < 64; ++k) {
                float a  = As[k * 33 + ty];
                float w0 = Ws[k * 33 + tx * 2];
                float w1 = Ws[k * 33 + tx * 2 + 1];
                acc0 = fmaf(a, w0, acc0);
                acc1 = fmaf(a, w1, acc1);
            }
            __syncthreads();
        }
        out[(size_t)(m0 + ty) * DMc + n0 + tx * 2]     = acc0 + bO[n0 + tx * 2];
        out[(size_t)(m0 + ty) * DMc + n0 + tx * 2 + 1] = acc1 + bO[n0 + tx * 2 + 1];
    }
}

// ===========================================================================
extern "C" void kernel_launch(void* const* d_in, const int* in_sizes, int n_in,
                              void* d_out, int out_size, void* d_ws, size_t ws_size,
                              hipStream_t stream) {
    (void)in_sizes; (void)n_in; (void)out_size; (void)ws_size;
    const float* x      = (const float*)d_in[0];
    const float* t      = (const float*)d_in[1];
    const float* WQ     = (const float*)d_in[2];
    const float* WK     = (const float*)d_in[3];
    const float* WV     = (const float*)d_in[4];
    const float* WO     = (const float*)d_in[5];
    const float* bO     = (const float*)d_in[6];
    const float* mu_abs = (const float*)d_in[7];
    const float* sg_abs = (const float*)d_in[8];
    const float* w_abs  = (const float*)d_in[9];
    const float* mu_rel = (const float*)d_in[10];
    const float* sg_rel = (const float*)d_in[11];
    const float* w_rel  = (const float*)d_in[12];
    const float* alpha  = (const float*)d_in[13];
    const float* beta   = (const float*)d_in[14];
    const float* gamma  = (const float*)d_in[15];
    float* out = (float*)d_out;
    float* ws = (float*)d_ws;

    float* Qb = ws;                // 131072 floats
    float* Kb = ws + 131072;
    float* Vb = ws + 262144;
    float* AO = ws + 393216;
    float* GA = ws + 524288;       // 4096
    float* GR = ws + 528384;       // 1048576 (logits)
    float4* TAB   = (float4*)(ws + 1576960);   // 32 x 512 x float4
    float4* NLIST = (float4*)(ws + 1642496);   // 32 x 128 x float4
    int*    NCNT  = (int*)   (ws + 1658880);   // 32 ints

    void* args[] = {
        (void*)&x, (void*)&t, (void*)&WQ, (void*)&WK, (void*)&WV, (void*)&WO, (void*)&bO,
        (void*)&mu_abs, (void*)&sg_abs, (void*)&w_abs,
        (void*)&mu_rel, (void*)&sg_rel, (void*)&w_rel,
        (void*)&alpha, (void*)&beta, (void*)&gamma,
        (void*)&out, (void*)&Qb, (void*)&Kb, (void*)&Vb,
        (void*)&AO, (void*)&GA, (void*)&GR,
        (void*)&TAB, (void*)&NLIST, (void*)&NCNT
    };
    hipLaunchCooperativeKernel((void*)k_fused, dim3(256), dim3(512), args, 0, stream);
}

// Round 9
// 123.825 us; speedup vs baseline: 2.9259x; 2.9259x over previous
//
#include <hip/hip_runtime.h>
#include <math.h>

constexpr int Bc = 2, Lc = 256, DMc = 256, Hc = 8, DHc = 32;
constexpr float LOG2E = 1.4426950408889634f;
constexpr float RSQRT_DH = 0.17677669529663687f; // 1/sqrt(32)
#define EXP2 __builtin_amdgcn_exp2f

// Gaussian-mixture tabulation parameters (see earlier rounds).
constexpr int   NTAB = 512;
constexpr float SIG0 = 0.02f;

// ===========================================================================
// role_tab: build per-(h,tau) piecewise-quadratic tables + narrow lists.
// 128 blocks = 32 (h,tau) x 4 chunks. Parallel narrow-list compaction.
// [R5 verbatim]
// ===========================================================================
__device__ __forceinline__ float mixsum(const float4* __restrict__ prm, float x) {
    float acc = 0.f;
    #pragma unroll 8
    for (int q = 0; q < 128; ++q) {
        float4 p = prm[q];          // (mu, n, w_masked, 0), wave-uniform ds_read
        float d0 = x - p.x;
        acc = fmaf(p.z, EXP2(d0 * d0 * p.y), acc);
    }
    return acc;
}

__device__ __forceinline__ void role_tab(int bx,
    const float* __restrict__ mu, const float* __restrict__ sg, const float* __restrict__ w,
    float4* __restrict__ TAB, float4* __restrict__ NLIST, int* __restrict__ NCNT,
    float* smem)
{
    float4* prm = (float4*)smem;      // 128 float4 = 512 floats
    float*  fs  = smem + 512;         // 260 floats
    int*    lcnt = (int*)(smem + 772);
    int hm = bx >> 2, chunk = bx & 3;      // hm = h*4+tau
    int h = hm >> 2, tau = hm & 3;
    int tid = threadIdx.x;

    if (tid == 0) *lcnt = 0;
    __syncthreads();
    if (tid < 128) {
        int d = tid >> 2, k = tid & 3;
        int off = h * 512 + d * 16 + tau * 4 + k;
        float s  = sg[off];
        float mv = mu[off], wv = w[off];
        float n = -(0.5f * LOG2E) / (s * s);
        bool narrow = (s < SIG0);
        prm[tid] = make_float4(mv, n, narrow ? 0.0f : wv, 0.0f);
        if (chunk == 0 && narrow) {
            int slot = atomicAdd(lcnt, 1);      // order irrelevant: summed later
            NLIST[hm * 128 + slot] = make_float4(mv, n, wv, 0.0f);
        }
    }
    __syncthreads();
    if (chunk == 0 && tid == 0) NCNT[hm] = *lcnt;

    // samples at x = (chunk*256 + s)/1024, s = 0..256
    fs[tid] = mixsum(prm, (float)(chunk * 256 + tid) * (1.0f / 1024.0f));
    if (tid == 0)
        fs[256] = mixsum(prm, (float)(chunk * 256 + 256) * (1.0f / 1024.0f));
    __syncthreads();

    if (tid < 128) {
        float f0 = fs[tid * 2], fm = fs[tid * 2 + 1], f1 = fs[tid * 2 + 2];
        float c2 = 2.0f * (f0 + f1 - 2.0f * fm);
        float c1 = f1 - f0 - c2;
        TAB[hm * NTAB + chunk * 128 + tid] = make_float4(f0, c1, c2, 0.0f);
    }
}

// ===========================================================================
// role_gabs (exact). [R5 verbatim]
// ===========================================================================
__device__ __forceinline__ void role_gabs(int idx, const float* __restrict__ t,
                                          const float* __restrict__ mu, const float* __restrict__ sg,
                                          const float* __restrict__ w, float* __restrict__ gabs,
                                          float* smem) {
    int h = idx & 7, b = (idx >> 3) & 1, q = idx >> 4;   // q: i-quarter
    int tid = threadIdx.x;
    {
        float2 s2 = *(const float2*)(sg + h * 512 + tid * 2);
        float2 o;
        o.x = -(0.5f * LOG2E) / (s2.x * s2.x);
        o.y = -(0.5f * LOG2E) / (s2.y * s2.y);
        *(float2*)(smem + tid * 2) = o;
    }
    __syncthreads();
    int lane = tid & 63, tg = tid >> 6;
    int i = q * 64 + lane;
    float tv = t[(b * Lc + i) * 4 + tg];
    const float* muB = mu + h * 512 + tg * 4;
    const float* wB  = w  + h * 512 + tg * 4;
    const float* nsB = smem + tg * 4;
    float acc = 0.f;
    #pragma unroll 4
    for (int d = 0; d < 32; ++d) {
        float4 m4 = *(const float4*)(muB + d * 16);
        float4 w4 = *(const float4*)(wB  + d * 16);
        float4 n4 = *(const float4*)(nsB + d * 16);
        float d0 = tv - m4.x; acc = fmaf(w4.x, EXP2(d0 * d0 * n4.x), acc);
        float d1 = tv - m4.y; acc = fmaf(w4.y, EXP2(d1 * d1 * n4.y), acc);
        float d2 = tv - m4.z; acc = fmaf(w4.z, EXP2(d2 * d2 * n4.z), acc);
        float d3 = tv - m4.w; acc = fmaf(w4.w, EXP2(d3 * d3 * n4.w), acc);
    }
    float* red = smem + 512;   // 4 x 64
    __syncthreads();
    red[tg * 64 + lane] = acc;
    __syncthreads();
    if (tid < 64)
        gabs[(b * Hc + h) * Lc + q * 64 + lane] =
            (red[lane] + red[64 + lane] + red[128 + lane] + red[192 + lane]) * (1.0f / 32.0f);
}

template<int R>
__device__ __forceinline__ void stage_tile2(const float* __restrict__ src, int ld,
                                            int row0, int k0, float* __restrict__ dst, int tid) {
    int row = tid >> 3;
    int cb = (tid & 7) * 2;
    float2 v = *(const float2*)(src + (size_t)(row0 + row) * ld + k0 + cb);
    dst[(cb + 0) * (R + 1) + row] = v.x;
    dst[(cb + 1) * (R + 1) + row] = v.y;
}

__device__ __forceinline__ void gemm32(const float* __restrict__ A, const float* __restrict__ W,
                                       float* __restrict__ C, const float* __restrict__ bias,
                                       float sc, int m0, int n0, float* smem) {
    // C[m0:+32, n0:+32] = sc * A[.,K=256] @ W^T (+bias); LDS [k][m] pitch 33.
    float* As = smem;
    float* Ws = smem + 16 * 33;
    int tid = threadIdx.x;
    int tx = tid & 15, ty = tid >> 4;
    float acc[2][2] = {};
    for (int k0 = 0; k0 < 256; k0 += 16) {
        stage_tile2<32>(A, 256, m0, k0, As, tid);
        stage_tile2<32>(W, 256, n0, k0, Ws, tid);
        __syncthreads();
        #pragma unroll
        for (int k = 0; k < 16; ++k) {
            float a0 = As[k * 33 + ty * 2], a1 = As[k * 33 + ty * 2 + 1];
            float w0 = Ws[k * 33 + tx * 2], w1 = Ws[k * 33 + tx * 2 + 1];
            acc[0][0] = fmaf(a0, w0, acc[0][0]);
            acc[0][1] = fmaf(a0, w1, acc[0][1]);
            acc[1][0] = fmaf(a1, w0, acc[1][0]);
            acc[1][1] = fmaf(a1, w1, acc[1][1]);
        }
        __syncthreads();
    }
    #pragma unroll
    for (int u = 0; u < 2; ++u) {
        int m = m0 + ty * 2 + u;
        #pragma unroll
        for (int v = 0; v < 2; ++v) {
            float o = acc[u][v] * sc;
            if (bias) o += bias[n0 + tx * 2 + v];
            C[(size_t)m * DMc + n0 + tx * 2 + v] = o;
        }
    }
}

// ===========================================================================
// k_pre: heterogeneous pre-work dispatch [R5 verbatim]:
//   [0,128)   tab, [128,192) gabs, [192,576) QKV gemm (32x32 tiles)
// ===========================================================================
__global__ void __launch_bounds__(256) k_pre(
    const float* __restrict__ x, const float* __restrict__ t,
    const float* __restrict__ WQ, const float* __restrict__ WK, const float* __restrict__ WV,
    const float* __restrict__ mu_a, const float* __restrict__ sg_a, const float* __restrict__ w_a,
    const float* __restrict__ mu_r, const float* __restrict__ sg_r, const float* __restrict__ w_r,
    float* __restrict__ Qb, float* __restrict__ Kb, float* __restrict__ Vb,
    float* __restrict__ GA,
    float4* __restrict__ TAB, float4* __restrict__ NLIST, int* __restrict__ NCNT)
{
    __shared__ __align__(16) float smem[1056];
    int bx = blockIdx.x;
    if (bx < 128) {
        role_tab(bx, mu_r, sg_r, w_r, TAB, NLIST, NCNT, smem);
    } else if (bx < 192) {
        role_gabs(bx - 128, t, mu_a, sg_a, w_a, GA, smem);
    } else {
        int idx = bx - 192;           // 0..383
        int z = idx >> 7;             // 0:Q 1:K 2:V
        int r = idx & 127;
        int m0 = (r >> 3) * 32, n0 = (r & 7) * 32;
        const float* W = (z == 0) ? WQ : (z == 1) ? WK : WV;
        float* C = (z == 0) ? Qb : (z == 1) ? Kb : Vb;
        gemm32(x, W, C, nullptr, (z == 0) ? RSQRT_DH : 1.0f, m0, n0, smem);
    }
}

// ===========================================================================
// k_att: merged k_sp + k_pvsm. One block = 16 i-rows x ALL 256 j for one bh.
// grid (16 it, 16 bh), block 512, 1 block/CU. Phases (LDS regions reused):
//   1. stage K^T,Xj^T ([k][264]), Q^T ([k][20])  -> MM: accS/accP (2x4/thread,
//      k-ascending FMA order == R5 k_sp, bitwise-identical logits)
//   2. stage V (K region, [j][34]) + per-head table (Xj region)
//   3. g_rel epilogue (R5 code, j0=0) -> logits -> in-register softmax
//      (row = 64 lanes of one wave, shfl width 64) -> probs to sP
//   4. PV from sP x V -> AO. GR logits never touch global memory.
// ===========================================================================
__global__ void __launch_bounds__(512) k_att(
    const float* __restrict__ Q, const float* __restrict__ K, const float* __restrict__ x,
    const float* __restrict__ t, const float* __restrict__ gabs,
    const float4* __restrict__ TAB, const float4* __restrict__ NLIST,
    const int* __restrict__ NCNT,
    const float* __restrict__ alpha, const float* __restrict__ beta, const float* __restrict__ gamma,
    const float* __restrict__ V, float* __restrict__ AO)
{
    __shared__ __align__(16) float sm[22224];   // 88.9 KB
    float* sK  = sm;            // [32][264] K^T  -> later V [256][34]
    float* sXj = sm + 8704;     // [32][264] Xj^T -> later table (float4[2048])
    float* sQ  = sm + 17408;    // [32][20]  Q^T
    float* sP  = sm + 18048;    // [16][260] probs
    float* sRS = sm + 22208;    // [16] 1/rowsum

    int it = blockIdx.x, bh = blockIdx.y;
    int b = bh >> 3, h = bh & 7;
    int i0 = it * 16;
    int tid = threadIdx.x;

    // ---- phase 1 staging: K^T, Xj^T (all j), Q rows ----
    {
        int r = tid >> 3, c4 = (tid & 7) * 4;
        #pragma unroll
        for (int u = 0; u < 4; ++u) {
            int j = r + u * 64;
            float4 kv = *(const float4*)(K + ((size_t)(b * Lc + j) * DMc + h * DHc + c4));
            float4 xj = *(const float4*)(x + ((size_t)(b * Lc + j) * DMc + h * DHc + c4));
            const float* k_ = (const float*)&kv; const float* x_ = (const float*)&xj;
            #pragma unroll
            for (int q = 0; q < 4; ++q) {
                sK [(c4 + q) * 264 + j] = k_[q];
                sXj[(c4 + q) * 264 + j] = x_[q];
            }
        }
        int i = tid >> 5, k = tid & 31;
        sQ[k * 20 + i] = Q[((size_t)(b * Lc + i0 + i) * DMc + h * DHc + k)];
    }
    __syncthreads();

    // ---- MM: S (Q pre-scaled) and P; 2x4 per thread, k ascending ----
    int tx = tid & 63, ty = tid >> 6;       // ty 0..7
    int i2 = ty * 2, j4 = tx * 4;
    float accS[2][4] = {}, accP[2][4] = {};
    #pragma unroll 4
    for (int k = 0; k < 32; ++k) {
        float2 qa = *(const float2*)(sQ  + k * 20  + i2);
        float2 xa = *(const float2*)(sXj + k * 264 + i0 + i2);   // Xi rows subset of Xj
        float4 kb = *(const float4*)(sK  + k * 264 + j4);
        float4 xb = *(const float4*)(sXj + k * 264 + j4);
        const float* qa_ = (const float*)&qa; const float* kb_ = (const float*)&kb;
        const float* xa_ = (const float*)&xa; const float* xb_ = (const float*)&xb;
        #pragma unroll
        for (int u = 0; u < 2; ++u)
            #pragma unroll
            for (int v = 0; v < 4; ++v) {
                accS[u][v] = fmaf(qa_[u], kb_[v], accS[u][v]);
                accP[u][v] = fmaf(xa_[u], xb_[v], accP[u][v]);
            }
    }
    __syncthreads();   // sK / sXj dead

    // ---- phase 2 staging: V into sK region, table into sXj region ----
    {
        int jr = tid >> 3, c4 = (tid & 7) * 4;
        #pragma unroll
        for (int u = 0; u < 4; ++u) {
            int j = jr + u * 64;
            *(float4*)(sK + j * 34 + c4) =
                *(const float4*)(V + ((size_t)(b * Lc + j) * DMc + h * DHc + c4));
        }
        float4* tab = (float4*)sXj;
        const float4* src = TAB + (size_t)h * 4 * NTAB;
        #pragma unroll
        for (int u = 0; u < 4; ++u)
            tab[tid + u * 512] = src[tid + u * 512];
    }
    __syncthreads();

    // ---- g_rel for this thread's 2x4 points (R5 epilogue, j0 = 0) ----
    float4* tab = (float4*)sXj;
    float4 tiv[2], tjv[4];
    #pragma unroll
    for (int u = 0; u < 2; ++u)
        tiv[u] = *(const float4*)(t + (size_t)(b * Lc + i0 + i2 + u) * 4);
    #pragma unroll
    for (int v = 0; v < 4; ++v)
        tjv[v] = *(const float4*)(t + (size_t)(b * Lc + j4 + v) * 4);

    float g8[2][4] = {};
    #pragma unroll
    for (int tg = 0; tg < 4; ++tg) {
        float xv[2][4];
        #pragma unroll
        for (int u = 0; u < 2; ++u) {
            float tiu = ((const float*)&tiv[u])[tg];
            #pragma unroll
            for (int v = 0; v < 4; ++v) {
                float xx = fabsf(tiu - ((const float*)&tjv[v])[tg]);
                xv[u][v] = xx;
                float xs = xx * (float)NTAB;
                int iu = min((int)xs, NTAB - 1);
                float uu = xs - (float)iu;
                float4 c = tab[tg * NTAB + iu];             // per-lane LDS gather
                g8[u][v] += fmaf(uu, fmaf(uu, c.z, c.y), c.x);
            }
        }
        int cn = NCNT[h * 4 + tg];                          // block-uniform
        for (int nn = 0; nn < cn; ++nn) {
            float4 q = NLIST[(h * 4 + tg) * 128 + nn];      // uniform s_load
            #pragma unroll
            for (int u = 0; u < 2; ++u)
                #pragma unroll
                for (int v = 0; v < 4; ++v) {
                    float d0 = xv[u][v] - q.x;
                    g8[u][v] = fmaf(q.z, EXP2(d0 * d0 * q.y), g8[u][v]);
                }
        }
    }

    // ---- modulation + in-register softmax (row == 64 lanes of this wave) ----
    float la = alpha[h], lb = beta[h], lg = gamma[h];
    constexpr float SC = 1.0f / 32.0f;
    #pragma unroll
    for (int u = 0; u < 2; ++u) {
        float gi2 = 2.0f * la * gabs[bh * Lc + i0 + i2 + u];
        float l0 = accS[u][0] * fmaf(accP[u][0], fmaf(lb, g8[u][0] * SC, gi2), lg);
        float l1 = accS[u][1] * fmaf(accP[u][1], fmaf(lb, g8[u][1] * SC, gi2), lg);
        float l2 = accS[u][2] * fmaf(accP[u][2], fmaf(lb, g8[u][2] * SC, gi2), lg);
        float l3 = accS[u][3] * fmaf(accP[u][3], fmaf(lb, g8[u][3] * SC, gi2), lg);
        float m = fmaxf(fmaxf(l0, l1), fmaxf(l2, l3));
        #pragma unroll
        for (int s = 1; s < 64; s <<= 1) m = fmaxf(m, __shfl_xor(m, s, 64));
        float4 e;
        e.x = EXP2((l0 - m) * LOG2E); e.y = EXP2((l1 - m) * LOG2E);
        e.z = EXP2((l2 - m) * LOG2E); e.w = EXP2((l3 - m) * LOG2E);
        float su = (e.x + e.y) + (e.z + e.w);
        #pragma unroll
        for (int s = 1; s < 64; s <<= 1) su += __shfl_xor(su, s, 64);
        *(float4*)(sP + (i2 + u) * 260 + j4) = e;
        if (tx == 0) sRS[i2 + u] = 1.0f / su;
    }
    __syncthreads();

    // ---- PV: thread (i, d) over all 256 j; V lives in sK region ----
    {
        int i = tid >> 5, d = tid & 31;
        float rs = sRS[i];
        float o0 = 0.f;
        #pragma unroll 4
        for (int jj = 0; jj < 256; jj += 4) {
            float4 p4 = *(const float4*)(sP + i * 260 + jj);
            o0 = fmaf(p4.x, sK[(jj + 0) * 34 + d], o0);
            o0 = fmaf(p4.y, sK[(jj + 1) * 34 + d], o0);
            o0 = fmaf(p4.z, sK[(jj + 2) * 34 + d], o0);
            o0 = fmaf(p4.w, sK[(jj + 3) * 34 + d], o0);
        }
        AO[((size_t)(b * Lc + i0 + i) * DMc + h * DHc + d)] = o0 * rs;
    }
}

// ===========================================================================
// kD: out = AO @ WO^T + bO.  grid (16,8), 32x32 tiles. [R5 verbatim]
// ===========================================================================
__global__ void __launch_bounds__(256) k_out(const float* __restrict__ A,
                                             const float* __restrict__ W,
                                             const float* __restrict__ bias,
                                             float* __restrict__ C) {
    __shared__ __align__(16) float smem[1056];
    gemm32(A, W, C, bias, 1.0f, blockIdx.x * 32, blockIdx.y * 32, smem);
}

// ===========================================================================
extern "C" void kernel_launch(void* const* d_in, const int* in_sizes, int n_in,
                              void* d_out, int out_size, void* d_ws, size_t ws_size,
                              hipStream_t stream) {
    (void)in_sizes; (void)n_in; (void)out_size; (void)ws_size;
    const float* x      = (const float*)d_in[0];
    const float* t      = (const float*)d_in[1];
    const float* WQ     = (const float*)d_in[2];
    const float* WK     = (const float*)d_in[3];
    const float* WV     = (const float*)d_in[4];
    const float* WO     = (const float*)d_in[5];
    const float* bO     = (const float*)d_in[6];
    const float* mu_abs = (const float*)d_in[7];
    const float* sg_abs = (const float*)d_in[8];
    const float* w_abs  = (const float*)d_in[9];
    const float* mu_rel = (const float*)d_in[10];
    const float* sg_rel = (const float*)d_in[11];
    const float* w_rel  = (const float*)d_in[12];
    const float* alpha  = (const float*)d_in[13];
    const float* beta   = (const float*)d_in[14];
    const float* gamma  = (const float*)d_in[15];
    float* out = (float*)d_out;
    float* ws = (float*)d_ws;

    float* Qb = ws;                // 131072 floats
    float* Kb = ws + 131072;
    float* Vb = ws + 262144;
    float* AO = ws + 393216;
    float* GA = ws + 524288;       // 4096
    // (old GR region ws+528384 now unused — logits never hit global)
    float4* TAB   = (float4*)(ws + 1576960);   // 32 x 512 x float4
    float4* NLIST = (float4*)(ws + 1642496);   // 32 x 128 x float4
    int*    NCNT  = (int*)   (ws + 1658880);   // 32 ints

    k_pre<<<dim3(576), dim3(256), 0, stream>>>(x, t, WQ, WK, WV,
                                               mu_abs, sg_abs, w_abs,
                                               mu_rel, sg_rel, w_rel,
                                               Qb, Kb, Vb, GA, TAB, NLIST, NCNT);
    k_att<<<dim3(16, 16), dim3(512), 0, stream>>>(Qb, Kb, x, t, GA,
                                                  TAB, NLIST, NCNT,
                                                  alpha, beta, gamma, Vb, AO);
    k_out<<<dim3(16, 8), dim3(256), 0, stream>>>(AO, WO, bO, out);
}